// Round 15
// baseline (285.939 us; speedup 1.0000x reference)
//
#include <hip/hip_runtime.h>

#define DH 128
#define ELLW 64

typedef __attribute__((ext_vector_type(8))) short short8;
typedef __attribute__((ext_vector_type(4))) float f32x4;

// ---- bf16 helpers (RNE pack, exact unpack) ----
__device__ inline unsigned f2bf(float f) {
    unsigned b = __float_as_uint(f);
    b += 0x7fff + ((b >> 16) & 1);
    return b >> 16;
}
__device__ inline float bflo(unsigned u) { return __uint_as_float(u << 16); }
__device__ inline float bfhi(unsigned u) { return __uint_as_float(u & 0xffff0000u); }

__device__ inline int wave_incl_scan(int v, int lane) {
#pragma unroll
    for (int off = 1; off < 64; off <<= 1) {
        int u = __shfl_up(v, off);
        if (lane >= off) v += u;
    }
    return v;
}

// ---------------- zero ----------------
__global__ __launch_bounds__(256) void k_zero_int(int* __restrict__ p, int n) {
    int i = blockIdx.x * 256 + threadIdx.x;
    if (i < n) p[i] = 0;
}

// ---------------- fused count + fill (ELL), XCD-partitioned ----------------
__global__ __launch_bounds__(256) void k_fill(const int* __restrict__ src,
                                              const int* __restrict__ dst,
                                              int* __restrict__ cnt,
                                              unsigned* __restrict__ ell,
                                              int nE, int ns) {
    int grp = blockIdx.x & 7;
    int blk = blockIdx.x >> 3;
    int nblk = gridDim.x >> 3;
    int lo = grp * ns, hi = lo + ns;
    for (int e = blk * 256 + threadIdx.x; e < nE; e += nblk * 256) {
        int d = dst[e];
        if (d >= lo && d < hi) {
            int slot = atomicAdd(&cnt[d], 1);
            if (slot < ELLW) ell[(size_t)d * ELLW + slot] = (unsigned)src[e];
        }
    }
}

// ---------------- inv = rsqrt(deg+1) ----------------
__global__ __launch_bounds__(256) void k_inv(const int* __restrict__ cnt,
                                             float* __restrict__ inv, int n) {
    int i = blockIdx.x * 256 + threadIdx.x;
    if (i < n) inv[i] = rsqrtf((float)(cnt[i] + 1));
}

// ---------------- degree histogram (65 bins) ----------------
__global__ __launch_bounds__(256) void k_hist(const int* __restrict__ cnt,
                                              int* __restrict__ hist, int n) {
    __shared__ int lh[65];
    if (threadIdx.x < 65) lh[threadIdx.x] = 0;
    __syncthreads();
    int i = blockIdx.x * 256 + threadIdx.x;
    if (i < n) atomicAdd(&lh[min(cnt[i], ELLW)], 1);
    __syncthreads();
    if (threadIdx.x < 65 && lh[threadIdx.x]) atomicAdd(&hist[threadIdx.x], lh[threadIdx.x]);
}

// single wave: exclusive-scan 65-bin hist -> bucket cursors
__global__ __launch_bounds__(64) void k_hscan(const int* __restrict__ hist,
                                              int* __restrict__ bcur) {
    int lane = threadIdx.x;
    int v = hist[lane];  // bins 0..63
    int incl = wave_incl_scan(v, lane);
    bcur[lane] = incl - v;
    if (lane == 63) bcur[64] = incl;  // base of bin 64 = total of 0..63
}

// ord: nodes in ascending-degree order
__global__ __launch_bounds__(256) void k_ord(const int* __restrict__ cnt,
                                             int* __restrict__ bcur,
                                             int* __restrict__ ord, int n) {
    int i = blockIdx.x * 256 + threadIdx.x;
    if (i < n) {
        int d = min(cnt[i], ELLW);
        int pos = atomicAdd(&bcur[d], 1);
        ord[pos] = i;
    }
}

// ---------------- MFMA GEMM: Cp[n,128 bf16-packed] = A[n,128] @ W[128,128] ----------------
// 64 rows/block, 4 waves x 16 rows. W staged once in LDS as bf16 transposed,
// 16B chunks swizzled by ((k/8 + c) & 15). A-frags straight from global.
// C/D layout (m89-verified): col = lane&15, row = (lane>>4)*4 + reg.
template <int AF32>
__global__ __launch_bounds__(256) void k_gemm_mfma(const void* __restrict__ Avoid,
                                                   const float* __restrict__ W,
                                                   unsigned* __restrict__ Cp, int n) {
    __shared__ unsigned Wl[64 * 128];  // 32KB
    int tid = threadIdx.x;

    // stage W^T bf16, swizzled; vectorized: 2x float4 loads -> 4 packed words
    for (int i = tid; i < 2048; i += 256) {
        int c4 = (i & 31) * 4;
        int k = (i >> 5) * 2;
        float4 fa = *(const float4*)&W[(size_t)k * DH + c4];
        float4 fb = *(const float4*)&W[(size_t)(k + 1) * DH + c4];
        int kb = (k >> 3), ksub = (k & 7) >> 1;
#pragma unroll
        for (int t = 0; t < 4; ++t) {
            int c = c4 + t;
            float a = (t == 0) ? fa.x : (t == 1) ? fa.y : (t == 2) ? fa.z : fa.w;
            float b = (t == 0) ? fb.x : (t == 1) ? fb.y : (t == 2) ? fb.z : fb.w;
            int ua = c * 64 + (((kb + c) & 15) << 2) + ksub;
            Wl[ua] = f2bf(a) | (f2bf(b) << 16);
        }
    }
    __syncthreads();

    int wid = tid >> 6, lane = tid & 63;
    int q = lane >> 4;
    int row0 = blockIdx.x * 64 + wid * 16;
    int r = row0 + (lane & 15);
    int rl = min(r, n - 1);

    short8 af[4];
    if (AF32) {
        const float* A = (const float*)Avoid;
#pragma unroll
        for (int ks = 0; ks < 4; ++ks) {
            const float* ap = &A[(size_t)rl * DH + ks * 32 + q * 8];
            float4 fa = *(const float4*)ap;
            float4 fb = *(const float4*)(ap + 4);
            short8 a;
            a[0] = (short)f2bf(fa.x); a[1] = (short)f2bf(fa.y);
            a[2] = (short)f2bf(fa.z); a[3] = (short)f2bf(fa.w);
            a[4] = (short)f2bf(fb.x); a[5] = (short)f2bf(fb.y);
            a[6] = (short)f2bf(fb.z); a[7] = (short)f2bf(fb.w);
            af[ks] = a;
        }
    } else {
        const unsigned* Ap = (const unsigned*)Avoid;
#pragma unroll
        for (int ks = 0; ks < 4; ++ks)
            af[ks] = *(const short8*)&Ap[(size_t)rl * 64 + ks * 16 + q * 4];
    }

    f32x4 acc[8];
#pragma unroll
    for (int cb = 0; cb < 8; ++cb) acc[cb] = (f32x4){0.f, 0.f, 0.f, 0.f};

#pragma unroll
    for (int cb = 0; cb < 8; ++cb) {
        int c = cb * 16 + (lane & 15);
#pragma unroll
        for (int ks = 0; ks < 4; ++ks) {
            int k0 = ks * 32 + q * 8;
            int ua = c * 64 + ((((k0 >> 3) + c) & 15) << 2);
            short8 bf = *(const short8*)&Wl[ua];
            acc[cb] = __builtin_amdgcn_mfma_f32_16x16x32_bf16(af[ks], bf, acc[cb], 0, 0, 0);
        }
    }

    __syncthreads();
    float* Cl = (float*)Wl;
#pragma unroll
    for (int cb = 0; cb < 8; ++cb) {
        int col = cb * 16 + (lane & 15);
#pragma unroll
        for (int reg = 0; reg < 4; ++reg) {
            int lrow = wid * 16 + q * 4 + reg;
            Cl[lrow * DH + col] = acc[cb][reg];
        }
    }
    __syncthreads();

    int base = blockIdx.x * 64;
    for (int i = tid; i < 64 * 64; i += 256) {
        int lrow = i >> 6, cu = i & 63;
        int grow = base + lrow;
        if (grow < n) {
            float v0 = Cl[lrow * DH + cu * 2];
            float v1 = Cl[lrow * DH + cu * 2 + 1];
            Cp[(size_t)grow * 64 + cu] = f2bf(v0) | (f2bf(v1) << 16);
        }
    }
}

// ---------------- fused gather + self-loop + bias + relu (+classifier) ----------------
// 16 lanes per node; deg-sorted node order via ord[] so the 4 quarters of a
// wave carry equal-degree nodes (removes max-of-4-Poisson wave-tail waste).
template <int FUSE_CLS>
__global__ __launch_bounds__(256) void k_gather(const unsigned* __restrict__ hp,
                                                const unsigned* __restrict__ ell,
                                                const int* __restrict__ cnt,
                                                const float* __restrict__ inv,
                                                const int* __restrict__ ord,
                                                const float* __restrict__ bias,
                                                unsigned* __restrict__ outp,
                                                const float* __restrict__ Wc,
                                                const float* __restrict__ bc,
                                                float* __restrict__ logits, int n) {
    int gq = (blockIdx.x * 256 + threadIdx.x) >> 4;
    int lq = threadIdx.x & 15;
    if (gq >= n) return;
    int node = ord[gq];

    int deg = min(cnt[node], ELLW);
    const unsigned* erow = &ell[(size_t)node * ELLW];
    float vi = inv[node];
    float sl = vi * vi;

    uint4 hs = *(const uint4*)&hp[(size_t)node * 64 + lq * 4];
    float ax[8];
    ax[0] = bflo(hs.x) * sl; ax[1] = bfhi(hs.x) * sl;
    ax[2] = bflo(hs.y) * sl; ax[3] = bfhi(hs.y) * sl;
    ax[4] = bflo(hs.z) * sl; ax[5] = bfhi(hs.z) * sl;
    ax[6] = bflo(hs.w) * sl; ax[7] = bfhi(hs.w) * sl;

    int j = 0;
    for (; j + 4 <= deg; j += 4) {
        unsigned s[4];
        float nf[4];
        uint4 u[4];
#pragma unroll
        for (int k = 0; k < 4; ++k) s[k] = erow[j + k];
#pragma unroll
        for (int k = 0; k < 4; ++k) nf[k] = inv[s[k]] * vi;
#pragma unroll
        for (int k = 0; k < 4; ++k)
            u[k] = *(const uint4*)&hp[(size_t)s[k] * 64 + lq * 4];
#pragma unroll
        for (int k = 0; k < 4; ++k) {
            ax[0] = fmaf(bflo(u[k].x), nf[k], ax[0]);
            ax[1] = fmaf(bfhi(u[k].x), nf[k], ax[1]);
            ax[2] = fmaf(bflo(u[k].y), nf[k], ax[2]);
            ax[3] = fmaf(bfhi(u[k].y), nf[k], ax[3]);
            ax[4] = fmaf(bflo(u[k].z), nf[k], ax[4]);
            ax[5] = fmaf(bfhi(u[k].z), nf[k], ax[5]);
            ax[6] = fmaf(bflo(u[k].w), nf[k], ax[6]);
            ax[7] = fmaf(bfhi(u[k].w), nf[k], ax[7]);
        }
    }
    for (; j < deg; ++j) {
        unsigned s = erow[j];
        float nf = inv[s] * vi;
        uint4 u = *(const uint4*)&hp[(size_t)s * 64 + lq * 4];
        ax[0] = fmaf(bflo(u.x), nf, ax[0]);
        ax[1] = fmaf(bfhi(u.x), nf, ax[1]);
        ax[2] = fmaf(bflo(u.y), nf, ax[2]);
        ax[3] = fmaf(bfhi(u.y), nf, ax[3]);
        ax[4] = fmaf(bflo(u.z), nf, ax[4]);
        ax[5] = fmaf(bfhi(u.z), nf, ax[5]);
        ax[6] = fmaf(bflo(u.w), nf, ax[6]);
        ax[7] = fmaf(bfhi(u.w), nf, ax[7]);
    }

    float4 b0 = *(const float4*)&bias[lq * 8];
    float4 b1 = *(const float4*)&bias[lq * 8 + 4];
    ax[0] = fmaxf(ax[0] + b0.x, 0.f); ax[1] = fmaxf(ax[1] + b0.y, 0.f);
    ax[2] = fmaxf(ax[2] + b0.z, 0.f); ax[3] = fmaxf(ax[3] + b0.w, 0.f);
    ax[4] = fmaxf(ax[4] + b1.x, 0.f); ax[5] = fmaxf(ax[5] + b1.y, 0.f);
    ax[6] = fmaxf(ax[6] + b1.z, 0.f); ax[7] = fmaxf(ax[7] + b1.w, 0.f);

    if (!FUSE_CLS) {
        uint4 o;
        o.x = f2bf(ax[0]) | (f2bf(ax[1]) << 16);
        o.y = f2bf(ax[2]) | (f2bf(ax[3]) << 16);
        o.z = f2bf(ax[4]) | (f2bf(ax[5]) << 16);
        o.w = f2bf(ax[6]) | (f2bf(ax[7]) << 16);
        *(uint4*)&outp[(size_t)node * 64 + lq * 4] = o;
    } else {
        float p0 = 0.f, p1 = 0.f;
#pragma unroll
        for (int m = 0; m < 4; ++m) {
            float4 w = *(const float4*)&Wc[lq * 16 + m * 4];
            p0 += ax[2 * m] * w.x + ax[2 * m + 1] * w.z;
            p1 += ax[2 * m] * w.y + ax[2 * m + 1] * w.w;
        }
#pragma unroll
        for (int off = 8; off > 0; off >>= 1) {
            p0 += __shfl_down(p0, off);
            p1 += __shfl_down(p1, off);
        }
        if (lq == 0) {
            logits[(size_t)node * 2 + 0] = p0 + bc[0];
            logits[(size_t)node * 2 + 1] = p1 + bc[1];
        }
    }
}

extern "C" void kernel_launch(void* const* d_in, const int* in_sizes, int n_in,
                              void* d_out, int out_size, void* d_ws, size_t ws_size,
                              hipStream_t stream) {
    const float* x  = (const float*)d_in[0];
    const int*   ei = (const int*)d_in[1];
    const float* W1 = (const float*)d_in[2];
    const float* b1 = (const float*)d_in[3];
    const float* W2 = (const float*)d_in[4];
    const float* b2 = (const float*)d_in[5];
    const float* Wc = (const float*)d_in[6];
    const float* bc = (const float*)d_in[7];
    float* out = (float*)d_out;

    int n  = in_sizes[0] / DH;
    int nE = in_sizes[1] / 2;
    const int* src = ei;
    const int* dst = ei + nE;

    size_t o = 0;
    auto alloc = [&](size_t bytes) {
        size_t r = o;
        o = (o + bytes + 255) & ~(size_t)255;
        return r;
    };
    char* ws = (char*)d_ws;
    size_t cnt_off = alloc((size_t)n * 4);
    size_t hist_off = alloc(65 * 4);
    size_t bcur_off = alloc(65 * 4);
    int*      cnt  = (int*)(ws + cnt_off);
    int*      hist = (int*)(ws + hist_off);
    int*      bcur = (int*)(ws + bcur_off);
    float*    inv  = (float*)(ws + alloc((size_t)n * 4));
    int*      ord  = (int*)(ws + alloc((size_t)n * 4));
    unsigned* ell  = (unsigned*)(ws + alloc((size_t)n * ELLW * 4));
    unsigned* hpA  = (unsigned*)(ws + alloc((size_t)n * 64 * 4));
    unsigned* hpB  = (unsigned*)(ws + alloc((size_t)n * 64 * 4));

    int zInts = (int)((bcur_off - cnt_off) / 4) + 65;  // cnt+hist+bcur contiguous zero
    int nB = (n + 255) / 256;
    int zB = (zInts + 255) / 256;
    int gemmB = (n + 63) / 64;
    int gatherB = (n + 15) / 16;
    int ns = (n + 7) / 8;

    // ELL build + degree sort
    k_zero_int<<<zB, 256, 0, stream>>>(cnt, zInts);
    k_fill<<<2048, 256, 0, stream>>>(src, dst, cnt, ell, nE, ns);
    k_inv<<<nB, 256, 0, stream>>>(cnt, inv, n);
    k_hist<<<nB, 256, 0, stream>>>(cnt, hist, n);
    k_hscan<<<1, 64, 0, stream>>>(hist, bcur);
    k_ord<<<nB, 256, 0, stream>>>(cnt, bcur, ord, n);

    // layer 1: hpA = bf16(x@W1); hpB = bf16(relu(agg + self + b1))
    k_gemm_mfma<1><<<gemmB, 256, 0, stream>>>(x, W1, hpA, n);
    k_gather<0><<<gatherB, 256, 0, stream>>>(hpA, ell, cnt, inv, ord, b1, hpB,
                                             nullptr, nullptr, nullptr, n);

    // layer 2: hpA = bf16(h1@W2); classifier fused into gather
    k_gemm_mfma<0><<<gemmB, 256, 0, stream>>>(hpB, W2, hpA, n);
    k_gather<1><<<gatherB, 256, 0, stream>>>(hpA, ell, cnt, inv, ord, b2, nullptr,
                                             Wc, bc, out, n);
}

// Round 17
// 140.509 us; speedup vs baseline: 2.0350x; 2.0350x over previous
//
#include <hip/hip_runtime.h>

#define DH 128
#define ELLW 64

typedef __attribute__((ext_vector_type(8))) short short8;
typedef __attribute__((ext_vector_type(4))) float f32x4;

// ---- bf16 helpers (RNE pack, exact unpack) ----
__device__ inline unsigned f2bf(float f) {
    unsigned b = __float_as_uint(f);
    b += 0x7fff + ((b >> 16) & 1);
    return b >> 16;
}
__device__ inline float bflo(unsigned u) { return __uint_as_float(u << 16); }
__device__ inline float bfhi(unsigned u) { return __uint_as_float(u & 0xffff0000u); }

// ---------------- zero ----------------
__global__ __launch_bounds__(256) void k_zero_int(int* __restrict__ p, int n) {
    int i = blockIdx.x * 256 + threadIdx.x;
    if (i < n) p[i] = 0;
}

// ---------------- fused count + fill (ELL) ----------------
// ELL: 64 slots/node. slot = atomicAdd(cnt[d]) gives both the degree count and
// the write position -> no rowptr/scan/cursor, one edge pass instead of two.
// XCD-partitioned (round 11): dst-space split into 8 ranges keyed by blockIdx%8
// so cnt/ell lines are written by one XCD's L2 (avoids cross-XCD line ping-pong).
__global__ __launch_bounds__(256) void k_fill(const int* __restrict__ src,
                                              const int* __restrict__ dst,
                                              int* __restrict__ cnt,
                                              unsigned* __restrict__ ell,
                                              int nE, int ns) {
    int grp = blockIdx.x & 7;
    int blk = blockIdx.x >> 3;
    int nblk = gridDim.x >> 3;
    int lo = grp * ns, hi = lo + ns;
    for (int e = blk * 256 + threadIdx.x; e < nE; e += nblk * 256) {
        int d = dst[e];
        if (d >= lo && d < hi) {
            int slot = atomicAdd(&cnt[d], 1);
            if (slot < ELLW) ell[(size_t)d * ELLW + slot] = (unsigned)src[e];
        }
    }
}

// ---------------- inv = rsqrt(deg+1) ----------------
__global__ __launch_bounds__(256) void k_inv(const int* __restrict__ cnt,
                                             float* __restrict__ inv, int n) {
    int i = blockIdx.x * 256 + threadIdx.x;
    if (i < n) inv[i] = rsqrtf((float)(cnt[i] + 1));
}

// ---------------- MFMA GEMM: Cp[n,128 bf16-packed] = A[n,128] @ W[128,128] ----------------
// 64 rows/block, 4 waves x 16 rows. W staged once in LDS as bf16 transposed,
// 16B chunks swizzled by ((k/8 + c) & 15). A-frags straight from global.
// C/D layout (m89-verified): col = lane&15, row = (lane>>4)*4 + reg.
template <int AF32>
__global__ __launch_bounds__(256) void k_gemm_mfma(const void* __restrict__ Avoid,
                                                   const float* __restrict__ W,
                                                   unsigned* __restrict__ Cp, int n) {
    __shared__ unsigned Wl[64 * 128];  // 32KB
    int tid = threadIdx.x;

    for (int i = tid; i < 128 * 64; i += 256) {
        int c = i & 127;
        int k = (i >> 7) * 2;
        float w0 = W[(size_t)k * DH + c];
        float w1 = W[(size_t)(k + 1) * DH + c];
        unsigned pk = f2bf(w0) | (f2bf(w1) << 16);
        int ua = c * 64 + ((((k >> 3) + c) & 15) << 2) + ((k & 7) >> 1);
        Wl[ua] = pk;
    }
    __syncthreads();

    int wid = tid >> 6, lane = tid & 63;
    int q = lane >> 4;
    int row0 = blockIdx.x * 64 + wid * 16;
    int r = row0 + (lane & 15);
    int rl = min(r, n - 1);

    short8 af[4];
    if (AF32) {
        const float* A = (const float*)Avoid;
#pragma unroll
        for (int ks = 0; ks < 4; ++ks) {
            const float* ap = &A[(size_t)rl * DH + ks * 32 + q * 8];
            float4 fa = *(const float4*)ap;
            float4 fb = *(const float4*)(ap + 4);
            short8 a;
            a[0] = (short)f2bf(fa.x); a[1] = (short)f2bf(fa.y);
            a[2] = (short)f2bf(fa.z); a[3] = (short)f2bf(fa.w);
            a[4] = (short)f2bf(fb.x); a[5] = (short)f2bf(fb.y);
            a[6] = (short)f2bf(fb.z); a[7] = (short)f2bf(fb.w);
            af[ks] = a;
        }
    } else {
        const unsigned* Ap = (const unsigned*)Avoid;
#pragma unroll
        for (int ks = 0; ks < 4; ++ks)
            af[ks] = *(const short8*)&Ap[(size_t)rl * 64 + ks * 16 + q * 4];
    }

    f32x4 acc[8];
#pragma unroll
    for (int cb = 0; cb < 8; ++cb) acc[cb] = (f32x4){0.f, 0.f, 0.f, 0.f};

#pragma unroll
    for (int cb = 0; cb < 8; ++cb) {
        int c = cb * 16 + (lane & 15);
#pragma unroll
        for (int ks = 0; ks < 4; ++ks) {
            int k0 = ks * 32 + q * 8;
            int ua = c * 64 + ((((k0 >> 3) + c) & 15) << 2);
            short8 bf = *(const short8*)&Wl[ua];
            acc[cb] = __builtin_amdgcn_mfma_f32_16x16x32_bf16(af[ks], bf, acc[cb], 0, 0, 0);
        }
    }

    __syncthreads();
    float* Cl = (float*)Wl;
#pragma unroll
    for (int cb = 0; cb < 8; ++cb) {
        int col = cb * 16 + (lane & 15);
#pragma unroll
        for (int reg = 0; reg < 4; ++reg) {
            int lrow = wid * 16 + q * 4 + reg;
            Cl[lrow * DH + col] = acc[cb][reg];
        }
    }
    __syncthreads();

    int base = blockIdx.x * 64;
    for (int i = tid; i < 64 * 64; i += 256) {
        int lrow = i >> 6, cu = i & 63;
        int grow = base + lrow;
        if (grow < n) {
            float v0 = Cl[lrow * DH + cu * 2];
            float v1 = Cl[lrow * DH + cu * 2 + 1];
            Cp[(size_t)grow * 64 + cu] = f2bf(v0) | (f2bf(v1) << 16);
        }
    }
}

// ---------------- fused gather + self-loop + bias + relu (+classifier) ----------------
// 16 lanes per node; lane holds 8 features (uint4 of packed bf16).
// ELL edges: row base node*64, deg = cnt[node]; norm = inv[src]*inv[node]
// computed here in fp32 (inv is L2-resident, 4B broadcast per edge-quarter).
template <int FUSE_CLS>
__global__ __launch_bounds__(256) void k_gather(const unsigned* __restrict__ hp,
                                                const unsigned* __restrict__ ell,
                                                const int* __restrict__ cnt,
                                                const float* __restrict__ inv,
                                                const float* __restrict__ bias,
                                                unsigned* __restrict__ outp,
                                                const float* __restrict__ Wc,
                                                const float* __restrict__ bc,
                                                float* __restrict__ logits, int n) {
    int node = (blockIdx.x * 256 + threadIdx.x) >> 4;
    int lq = threadIdx.x & 15;
    if (node >= n) return;

    int deg = min(cnt[node], ELLW);
    const unsigned* erow = &ell[(size_t)node * ELLW];
    float vi = inv[node];
    float sl = vi * vi;

    uint4 hs = *(const uint4*)&hp[(size_t)node * 64 + lq * 4];
    float ax[8];
    ax[0] = bflo(hs.x) * sl; ax[1] = bfhi(hs.x) * sl;
    ax[2] = bflo(hs.y) * sl; ax[3] = bfhi(hs.y) * sl;
    ax[4] = bflo(hs.z) * sl; ax[5] = bfhi(hs.z) * sl;
    ax[6] = bflo(hs.w) * sl; ax[7] = bfhi(hs.w) * sl;

    int j = 0;
    for (; j + 4 <= deg; j += 4) {
        unsigned s[4];
        float nf[4];
        uint4 u[4];
#pragma unroll
        for (int k = 0; k < 4; ++k) s[k] = erow[j + k];
#pragma unroll
        for (int k = 0; k < 4; ++k) nf[k] = inv[s[k]] * vi;
#pragma unroll
        for (int k = 0; k < 4; ++k)
            u[k] = *(const uint4*)&hp[(size_t)s[k] * 64 + lq * 4];
#pragma unroll
        for (int k = 0; k < 4; ++k) {
            ax[0] = fmaf(bflo(u[k].x), nf[k], ax[0]);
            ax[1] = fmaf(bfhi(u[k].x), nf[k], ax[1]);
            ax[2] = fmaf(bflo(u[k].y), nf[k], ax[2]);
            ax[3] = fmaf(bfhi(u[k].y), nf[k], ax[3]);
            ax[4] = fmaf(bflo(u[k].z), nf[k], ax[4]);
            ax[5] = fmaf(bfhi(u[k].z), nf[k], ax[5]);
            ax[6] = fmaf(bflo(u[k].w), nf[k], ax[6]);
            ax[7] = fmaf(bfhi(u[k].w), nf[k], ax[7]);
        }
    }
    for (; j < deg; ++j) {
        unsigned s = erow[j];
        float nf = inv[s] * vi;
        uint4 u = *(const uint4*)&hp[(size_t)s * 64 + lq * 4];
        ax[0] = fmaf(bflo(u.x), nf, ax[0]);
        ax[1] = fmaf(bfhi(u.x), nf, ax[1]);
        ax[2] = fmaf(bflo(u.y), nf, ax[2]);
        ax[3] = fmaf(bfhi(u.y), nf, ax[3]);
        ax[4] = fmaf(bflo(u.z), nf, ax[4]);
        ax[5] = fmaf(bfhi(u.z), nf, ax[5]);
        ax[6] = fmaf(bflo(u.w), nf, ax[6]);
        ax[7] = fmaf(bfhi(u.w), nf, ax[7]);
    }

    float4 b0 = *(const float4*)&bias[lq * 8];
    float4 b1 = *(const float4*)&bias[lq * 8 + 4];
    ax[0] = fmaxf(ax[0] + b0.x, 0.f); ax[1] = fmaxf(ax[1] + b0.y, 0.f);
    ax[2] = fmaxf(ax[2] + b0.z, 0.f); ax[3] = fmaxf(ax[3] + b0.w, 0.f);
    ax[4] = fmaxf(ax[4] + b1.x, 0.f); ax[5] = fmaxf(ax[5] + b1.y, 0.f);
    ax[6] = fmaxf(ax[6] + b1.z, 0.f); ax[7] = fmaxf(ax[7] + b1.w, 0.f);

    if (!FUSE_CLS) {
        uint4 o;
        o.x = f2bf(ax[0]) | (f2bf(ax[1]) << 16);
        o.y = f2bf(ax[2]) | (f2bf(ax[3]) << 16);
        o.z = f2bf(ax[4]) | (f2bf(ax[5]) << 16);
        o.w = f2bf(ax[6]) | (f2bf(ax[7]) << 16);
        *(uint4*)&outp[(size_t)node * 64 + lq * 4] = o;
    } else {
        float p0 = 0.f, p1 = 0.f;
#pragma unroll
        for (int m = 0; m < 4; ++m) {
            float4 w = *(const float4*)&Wc[lq * 16 + m * 4];
            p0 += ax[2 * m] * w.x + ax[2 * m + 1] * w.z;
            p1 += ax[2 * m] * w.y + ax[2 * m + 1] * w.w;
        }
#pragma unroll
        for (int off = 8; off > 0; off >>= 1) {
            p0 += __shfl_down(p0, off);
            p1 += __shfl_down(p1, off);
        }
        if (lq == 0) {
            logits[(size_t)node * 2 + 0] = p0 + bc[0];
            logits[(size_t)node * 2 + 1] = p1 + bc[1];
        }
    }
}

extern "C" void kernel_launch(void* const* d_in, const int* in_sizes, int n_in,
                              void* d_out, int out_size, void* d_ws, size_t ws_size,
                              hipStream_t stream) {
    const float* x  = (const float*)d_in[0];
    const int*   ei = (const int*)d_in[1];
    const float* W1 = (const float*)d_in[2];
    const float* b1 = (const float*)d_in[3];
    const float* W2 = (const float*)d_in[4];
    const float* b2 = (const float*)d_in[5];
    const float* Wc = (const float*)d_in[6];
    const float* bc = (const float*)d_in[7];
    float* out = (float*)d_out;

    int n  = in_sizes[0] / DH;
    int nE = in_sizes[1] / 2;
    const int* src = ei;
    const int* dst = ei + nE;

    size_t o = 0;
    auto alloc = [&](size_t bytes) {
        size_t r = o;
        o = (o + bytes + 255) & ~(size_t)255;
        return r;
    };
    char* ws = (char*)d_ws;
    int*      cnt = (int*)(ws + alloc((size_t)n * 4));
    float*    inv = (float*)(ws + alloc((size_t)n * 4));
    unsigned* ell = (unsigned*)(ws + alloc((size_t)n * ELLW * 4));  // 12.8MB
    unsigned* hpA = (unsigned*)(ws + alloc((size_t)n * 64 * 4));
    unsigned* hpB = (unsigned*)(ws + alloc((size_t)n * 64 * 4));

    int nB = (n + 255) / 256;
    int gemmB = (n + 63) / 64;
    int gatherB = (n + 15) / 16;
    int ns = (n + 7) / 8;

    // ELL build: zero counts -> fused count+fill -> inv
    k_zero_int<<<nB, 256, 0, stream>>>(cnt, n);
    k_fill<<<2048, 256, 0, stream>>>(src, dst, cnt, ell, nE, ns);
    k_inv<<<nB, 256, 0, stream>>>(cnt, inv, n);

    // layer 1: hpA = bf16(x@W1); hpB = bf16(relu(agg + self + b1))
    k_gemm_mfma<1><<<gemmB, 256, 0, stream>>>(x, W1, hpA, n);
    k_gather<0><<<gatherB, 256, 0, stream>>>(hpA, ell, cnt, inv, b1, hpB,
                                             nullptr, nullptr, nullptr, n);

    // layer 2: hpA = bf16(h1@W2); classifier fused into gather
    k_gemm_mfma<0><<<gemmB, 256, 0, stream>>>(hpB, W2, hpA, n);
    k_gather<1><<<gatherB, 256, 0, stream>>>(hpA, ell, cnt, inv, b2, nullptr,
                                             Wc, bc, out, n);
}